// Round 7
// baseline (281.996 us; speedup 1.0000x reference)
//
#include <hip/hip_runtime.h>

// TransformerBlock on MI355X (gfx950).
// Fused in-proj (q,k from RoPE(x); v from x, written transposed), 16-head
// flash attention (D=64): 32x32x16 MFMA, S^T = K·Q^T, P stays in registers
// (V key-columns permuted in LDS so PV A-frag = S^T C-quads directly).
// v8: key-split waves (block = 64 q x 4 waves = qhalf x keyhalf) -> 16
// waves/CU; permuted-V staging via gathered global b64 loads + contiguous
// swizzled b128 LDS writes (conflict-free); O/l combined across key-half
// wave pairs at the end. Then out-proj, res+LN1, GeGLU, res+LN2.

typedef __bf16 bf16;
typedef bf16 bf16x8 __attribute__((ext_vector_type(8)));
typedef bf16 bf16x4 __attribute__((ext_vector_type(4)));
typedef float f32x4 __attribute__((ext_vector_type(4)));
typedef float f32x16 __attribute__((ext_vector_type(16)));

#define EMB 1024
#define SEQ 2048
#define NTOK 4096
#define NH 16
#define HD 64

__device__ __forceinline__ f32x4 mfma16(bf16x8 a, bf16x8 b, f32x4 c) {
  return __builtin_amdgcn_mfma_f32_16x16x32_bf16(a, b, c, 0, 0, 0);
}
__device__ __forceinline__ f32x16 mfma32(bf16x8 a, bf16x8 b, f32x16 c) {
  return __builtin_amdgcn_mfma_f32_32x32x16_bf16(a, b, c, 0, 0, 0);
}

__device__ __forceinline__ void gll16(const void* g, void* l) {
  __builtin_amdgcn_global_load_lds(
      (const __attribute__((address_space(1))) void*)g,
      (__attribute__((address_space(3))) void*)l, 16, 0, 0);
}

__device__ __forceinline__ unsigned pk2(float a, float b) {
  union { bf16 h[2]; unsigned u; } t;
  t.h[0] = (bf16)a; t.h[1] = (bf16)b;
  return t.u;
}

// ---------------- elementwise prep ----------------

__global__ __launch_bounds__(256) void rope_cast(
    const float* __restrict__ x, bf16* __restrict__ xb, bf16* __restrict__ qr) {
  int idx = blockIdx.x * 256 + threadIdx.x;   // 0 .. NTOK*512
  int row = idx >> 9;
  int i = idx & 511;
  int h = i >> 5, d2 = i & 31;
  int pos = row & (SEQ - 1);
  int c0 = h * HD + d2;
  size_t base = (size_t)row * EMB;
  float x0 = x[base + c0], x1 = x[base + c0 + 32];
  float invf = exp2f(-(float)d2 * 0.4152410118609203f);
  float ang = (float)pos * invf;
  float sn, cs;
  sincosf(ang, &sn, &cs);
  qr[base + c0] = (bf16)(x0 * cs - x1 * sn);
  qr[base + c0 + 32] = (bf16)(x1 * cs + x0 * sn);
  xb[base + c0] = (bf16)x0;
  xb[base + c0 + 32] = (bf16)x1;
}

__global__ __launch_bounds__(256) void cast_w(
    const float* __restrict__ w, bf16* __restrict__ o, int n) {
  int i = (blockIdx.x * 256 + threadIdx.x) * 4;
  if (i < n) {
    float4 f = *(const float4*)(w + i);
    o[i] = (bf16)f.x; o[i + 1] = (bf16)f.y;
    o[i + 2] = (bf16)f.z; o[i + 3] = (bf16)f.w;
  }
}

// ---------------- fused in-proj GEMM ----------------
__global__ __launch_bounds__(256) void gemm_in(
    const bf16* __restrict__ Aq, const bf16* __restrict__ Ax,
    const bf16* __restrict__ W, const float* __restrict__ bias,
    bf16* __restrict__ qk, bf16* __restrict__ vT) {
  __shared__ bf16 As[128 * 32];
  __shared__ bf16 Bs[128 * 32];
  const int tid = threadIdx.x, lane = tid & 63, wave = tid >> 6;
  const int quad = lane >> 4, l16 = lane & 15;
  const int m0 = blockIdx.y * 128, n0 = blockIdx.x * 128;
  const bf16* A = (n0 < 2048) ? Aq : Ax;
  const int K = 1024;
  const int wm = (wave >> 1) * 64, wn = (wave & 1) * 64;
  const int srow = wave * 32 + (lane >> 2);
  const int scol = (lane & 3) * 8;
  f32x4 acc[4][4] = {};
  for (int k0 = 0; k0 < K; k0 += 32) {
    __syncthreads();
    gll16(A + (size_t)(m0 + srow) * K + k0 + scol, As + wave * 1024);
    gll16(A + (size_t)(m0 + srow + 16) * K + k0 + scol, As + wave * 1024 + 512);
    gll16(W + (size_t)(n0 + srow) * K + k0 + scol, Bs + wave * 1024);
    gll16(W + (size_t)(n0 + srow + 16) * K + k0 + scol, Bs + wave * 1024 + 512);
    __syncthreads();
    bf16x8 af[4], bw[4];
#pragma unroll
    for (int t = 0; t < 4; ++t) {
      af[t] = *(const bf16x8*)(As + (wm + t * 16 + l16) * 32 + quad * 8);
      bw[t] = *(const bf16x8*)(Bs + (wn + t * 16 + l16) * 32 + quad * 8);
    }
#pragma unroll
    for (int mt = 0; mt < 4; ++mt)
#pragma unroll
      for (int nt = 0; nt < 4; ++nt)
        acc[mt][nt] = mfma16(af[mt], bw[nt], acc[mt][nt]);
  }
  if (n0 < 2048) {
#pragma unroll
    for (int mt = 0; mt < 4; ++mt)
      for (int nt = 0; nt < 4; ++nt) {
        const int n = n0 + wn + nt * 16 + l16;
        const float bv = bias[n];
#pragma unroll
        for (int r = 0; r < 4; ++r) {
          const int m = m0 + wm + mt * 16 + quad * 4 + r;
          qk[(size_t)m * 2048 + n] = (bf16)(acc[mt][nt][r] + bv);
        }
      }
  } else {
#pragma unroll
    for (int mt = 0; mt < 4; ++mt)
      for (int nt = 0; nt < 4; ++nt) {
        const int n = n0 + wn + nt * 16 + l16;
        const float bv = bias[n];
        const int m = m0 + wm + mt * 16 + quad * 4;
        const int bb = m >> 11, s = m & 2047;
        bf16x4 pkv;
#pragma unroll
        for (int r = 0; r < 4; ++r) pkv[r] = (bf16)(acc[mt][nt][r] + bv);
        *(bf16x4*)(vT + (((size_t)bb * 1024 + (n - 2048)) << 11) + s) = pkv;
      }
  }
}

// ---------------- GEMM 128x128: C = A @ W^T + bias ----------------
__global__ __launch_bounds__(256) void gemm_bt(
    const bf16* __restrict__ A, const bf16* __restrict__ W,
    const float* __restrict__ bias,
    float* __restrict__ outF, bf16* __restrict__ outB,
    int M, int N, int K) {
  __shared__ bf16 As[128 * 32];
  __shared__ bf16 Bs[128 * 32];
  const int tid = threadIdx.x, lane = tid & 63, wave = tid >> 6;
  const int quad = lane >> 4, l16 = lane & 15;
  const int m0 = blockIdx.y * 128, n0 = blockIdx.x * 128;
  const int wm = (wave >> 1) * 64, wn = (wave & 1) * 64;
  const int srow = wave * 32 + (lane >> 2);
  const int scol = (lane & 3) * 8;
  f32x4 acc[4][4] = {};
  for (int k0 = 0; k0 < K; k0 += 32) {
    __syncthreads();
    gll16(A + (size_t)(m0 + srow) * K + k0 + scol, As + wave * 1024);
    gll16(A + (size_t)(m0 + srow + 16) * K + k0 + scol, As + wave * 1024 + 512);
    gll16(W + (size_t)(n0 + srow) * K + k0 + scol, Bs + wave * 1024);
    gll16(W + (size_t)(n0 + srow + 16) * K + k0 + scol, Bs + wave * 1024 + 512);
    __syncthreads();
    bf16x8 af[4], bw[4];
#pragma unroll
    for (int t = 0; t < 4; ++t) {
      af[t] = *(const bf16x8*)(As + (wm + t * 16 + l16) * 32 + quad * 8);
      bw[t] = *(const bf16x8*)(Bs + (wn + t * 16 + l16) * 32 + quad * 8);
    }
#pragma unroll
    for (int mt = 0; mt < 4; ++mt)
#pragma unroll
      for (int nt = 0; nt < 4; ++nt)
        acc[mt][nt] = mfma16(af[mt], bw[nt], acc[mt][nt]);
  }
#pragma unroll
  for (int mt = 0; mt < 4; ++mt)
    for (int nt = 0; nt < 4; ++nt) {
      const int n = n0 + wn + nt * 16 + l16;
      const float bv = bias ? bias[n] : 0.0f;
#pragma unroll
      for (int r = 0; r < 4; ++r) {
        const int m = m0 + wm + mt * 16 + quad * 4 + r;
        const float v = acc[mt][nt][r] + bv;
        if (outF) outF[(size_t)m * N + n] = v;
        if (outB) outB[(size_t)m * N + n] = (bf16)v;
      }
    }
}

// ---------------- GEMM 128x64 tiles ----------------
__global__ __launch_bounds__(256) void gemm_bt64(
    const bf16* __restrict__ A, const bf16* __restrict__ W,
    const float* __restrict__ bias, float* __restrict__ outF,
    int M, int N, int K) {
  __shared__ bf16 As[128 * 32];
  __shared__ bf16 Bs[64 * 32];
  const int tid = threadIdx.x, lane = tid & 63, wave = tid >> 6;
  const int quad = lane >> 4, l16 = lane & 15;
  const int m0 = blockIdx.y * 128, n0 = blockIdx.x * 64;
  const int wm = (wave >> 1) * 64, wn = (wave & 1) * 32;
  const int srow = wave * 32 + (lane >> 2);
  const int srowB = wave * 16 + (lane >> 2);
  const int scol = (lane & 3) * 8;
  f32x4 acc[4][2] = {};
  for (int k0 = 0; k0 < K; k0 += 32) {
    __syncthreads();
    gll16(A + (size_t)(m0 + srow) * K + k0 + scol, As + wave * 1024);
    gll16(A + (size_t)(m0 + srow + 16) * K + k0 + scol, As + wave * 1024 + 512);
    gll16(W + (size_t)(n0 + srowB) * K + k0 + scol, Bs + wave * 512);
    __syncthreads();
    bf16x8 af[4], bw[2];
#pragma unroll
    for (int t = 0; t < 4; ++t)
      af[t] = *(const bf16x8*)(As + (wm + t * 16 + l16) * 32 + quad * 8);
#pragma unroll
    for (int t = 0; t < 2; ++t)
      bw[t] = *(const bf16x8*)(Bs + (wn + t * 16 + l16) * 32 + quad * 8);
#pragma unroll
    for (int mt = 0; mt < 4; ++mt)
#pragma unroll
      for (int nt = 0; nt < 2; ++nt)
        acc[mt][nt] = mfma16(af[mt], bw[nt], acc[mt][nt]);
  }
#pragma unroll
  for (int mt = 0; mt < 4; ++mt)
    for (int nt = 0; nt < 2; ++nt) {
      const int n = n0 + wn + nt * 16 + l16;
      const float bv = bias[n];
#pragma unroll
      for (int r = 0; r < 4; ++r) {
        const int m = m0 + wm + mt * 16 + quad * 4 + r;
        outF[(size_t)m * N + n] = acc[mt][nt][r] + bv;
      }
    }
}

// ---------------- flash attention v8: key-split waves ----------------
// 1024 blocks (XCD-swizzled), block = 64 q-rows, 4 waves = (qgrp, khalf).
// Each wave: 32 q x 32 keys per 64-key tile: 4 S-MFMAs + 16 exp + 4 PV-MFMAs.
// V permuted per-16 keys [0-3,8-11,4-7,12-15] via gathered global b64 loads,
// written as contiguous swizzled b128 (conflict-free, same pattern as K).
// O/l partials combined across key-half wave pairs at the end (LDS reuse).
__global__ __launch_bounds__(256) void attn8(
    const bf16* __restrict__ QK, const bf16* __restrict__ VT,
    bf16* __restrict__ ctx) {
  __shared__ __align__(16) bf16 Ks[2][4096];
  __shared__ __align__(16) bf16 Vs[2][4096];
  __shared__ float Linv2[2][32];
  const int tid = threadIdx.x, lane = tid & 63, wave = tid >> 6;
  const int hi = lane >> 5, l31 = lane & 31, l7 = lane & 7;
  const int qgrp = wave & 1, khalf = wave >> 1;
  const int bid = blockIdx.x;
  const int hb = (bid & 7) * 4 + ((bid >> 3) & 3);
  const int qt = bid >> 5;              // 0..31
  const int h = hb & 15, b = hb >> 4;

  // Q B-frags (lane owns col q = qgrp*32+l31; k=d=tt*16+hi*8+j), scaled 0.125
  bf16x8 qf[4];
  {
    const int qrow = qt * 64 + qgrp * 32 + l31;
    const bf16* qp = QK + (size_t)(b * SEQ + qrow) * 2048 + h * HD + hi * 8;
#pragma unroll
    for (int t = 0; t < 4; ++t) {
      bf16x8 v = *(const bf16x8*)(qp + t * 16);
#pragma unroll
      for (int j = 0; j < 8; ++j) v[j] = (bf16)((float)v[j] * 0.125f);
      qf[t] = v;
    }
  }
  f32x16 o0 = {}, o1 = {};
  float lpart = 0.0f;

  const int srow = tid >> 3;   // 0..31 staging row (d for V, key for K)
  const int sc16 = tid & 7;    // 16B chunk 0..7
  const int tq = sc16 >> 1;
  const int og = tq * 16 + (sc16 & 1) * 4;   // permuted V gather base
  const bf16* kg = QK + (size_t)(b * SEQ) * 2048 + 1024 + h * HD + sc16 * 8;
  const bf16* vgr = VT + ((size_t)(b * NH + h) * HD) * 2048;

  bf16x8 kcur[2];
  uint2 va[2], vb[2];
#pragma unroll
  for (int p = 0; p < 2; ++p) {   // tile 0 loads
    const int row = p * 32 + srow;
    kcur[p] = *(const bf16x8*)(kg + (size_t)row * 2048);
    va[p] = *(const uint2*)(vgr + (size_t)row * 2048 + og);
    vb[p] = *(const uint2*)(vgr + (size_t)row * 2048 + og + 8);
  }
#pragma unroll
  for (int p = 0; p < 2; ++p) {   // stage tile 0 into buf 0
    const int row = p * 32 + srow;
    const int sw = row * 64 + ((sc16 ^ (row & 7)) * 8);
    *(bf16x8*)(Ks[0] + sw) = kcur[p];
    union { uint2 u2[2]; bf16x8 v; } vv;
    vv.u2[0] = va[p]; vv.u2[1] = vb[p];
    *(bf16x8*)(Vs[0] + sw) = vv.v;
  }
#pragma unroll
  for (int p = 0; p < 2; ++p) {   // prefetch tile 1
    const int row = p * 32 + srow;
    kcur[p] = *(const bf16x8*)(kg + (size_t)(64 + row) * 2048);
    va[p] = *(const uint2*)(vgr + (size_t)row * 2048 + 64 + og);
    vb[p] = *(const uint2*)(vgr + (size_t)row * 2048 + 64 + og + 8);
  }

  for (int t = 0; t < 32; ++t) {
    __syncthreads();
    const bf16* ks = Ks[t & 1];
    const bf16* vs = Vs[t & 1];
    if (t + 1 < 32) {
      bf16* kd = Ks[(t + 1) & 1];
      bf16* vd = Vs[(t + 1) & 1];
#pragma unroll
      for (int p = 0; p < 2; ++p) {
        const int row = p * 32 + srow;
        const int sw = row * 64 + ((sc16 ^ (row & 7)) * 8);
        *(bf16x8*)(kd + sw) = kcur[p];
        union { uint2 u2[2]; bf16x8 v; } vv;
        vv.u2[0] = va[p]; vv.u2[1] = vb[p];
        *(bf16x8*)(vd + sw) = vv.v;
      }
      if (t + 2 < 32) {
        const int kb2 = (t + 2) * 64;
#pragma unroll
        for (int p = 0; p < 2; ++p) {
          const int row = p * 32 + srow;
          kcur[p] = *(const bf16x8*)(kg + (size_t)(kb2 + row) * 2048);
          va[p] = *(const uint2*)(vgr + (size_t)row * 2048 + kb2 + og);
          vb[p] = *(const uint2*)(vgr + (size_t)row * 2048 + kb2 + og + 8);
        }
      }
    }
    // S^T[key = khalf*32 + l31][q]
    f32x16 s0 = {};
#pragma unroll
    for (int tt = 0; tt < 4; ++tt) {
      bf16x8 kf = *(const bf16x8*)(
          ks + (khalf * 32 + l31) * 64 + (((tt * 2 + hi) ^ l7) * 8));
      s0 = mfma32(kf, qf[tt], s0);
    }
    // exp -> u[2g],u[2g+1] = quad g = keys khalf*32 + 8g + 4hi + {0..3}
    unsigned u[8];
#pragma unroll
    for (int g = 0; g < 4; ++g) {
      float e0 = __expf(s0[g * 4]);
      float e1 = __expf(s0[g * 4 + 1]);
      float e2 = __expf(s0[g * 4 + 2]);
      float e3 = __expf(s0[g * 4 + 3]);
      lpart += (e0 + e1) + (e2 + e3);
      u[g * 2] = pk2(e0, e1);
      u[g * 2 + 1] = pk2(e2, e3);
    }
    // PV: chunks kk = 2*khalf + {0,1}; A-frag = u[4kl..4kl+3] directly
#pragma unroll
    for (int kl = 0; kl < 2; ++kl) {
      const int kk = 2 * khalf + kl;
      union { unsigned w[4]; bf16x8 v; } fw;
      fw.w[0] = u[4 * kl]; fw.w[1] = u[4 * kl + 1];
      fw.w[2] = u[4 * kl + 2]; fw.w[3] = u[4 * kl + 3];
      const int swz = (4 * kk + 2 * hi) ^ (l7 << 1);
      bf16x8 v0 = *(const bf16x8*)(vs + l31 * 64 + swz * 4);
      bf16x8 v1 = *(const bf16x8*)(vs + (32 + l31) * 64 + swz * 4);
      o0 = mfma32(fw.v, v0, o0);
      o1 = mfma32(fw.v, v1, o1);
    }
  }
  // combine across key-half wave pairs (reuse Ks as O buffer, Vs for l)
  __syncthreads();
  float* Osh = (float*)Ks;
  float* Lsh = (float*)Vs;
  if (khalf) {
    float* ob = Osh + qgrp * 2048;
#pragma unroll
    for (int c = 0; c < 4; ++c) {
      f32x4 t0 = {o0[4 * c], o0[4 * c + 1], o0[4 * c + 2], o0[4 * c + 3]};
      f32x4 t1 = {o1[4 * c], o1[4 * c + 1], o1[4 * c + 2], o1[4 * c + 3]};
      *(f32x4*)(ob + c * 256 + lane * 4) = t0;
      *(f32x4*)(ob + 1024 + c * 256 + lane * 4) = t1;
    }
    Lsh[qgrp * 64 + lane] = lpart;
  }
  __syncthreads();
  if (!khalf) {
    float* ob = Osh + qgrp * 2048;
#pragma unroll
    for (int c = 0; c < 4; ++c) {
      f32x4 t0 = *(const f32x4*)(ob + c * 256 + lane * 4);
      f32x4 t1 = *(const f32x4*)(ob + 1024 + c * 256 + lane * 4);
#pragma unroll
      for (int j = 0; j < 4; ++j) {
        o0[4 * c + j] += t0[j];
        o1[4 * c + j] += t1[j];
      }
    }
    lpart += Lsh[qgrp * 64 + lane];
    float ltot = lpart + __shfl_xor(lpart, 32, 64);
    if (lane < 32) Linv2[qgrp][lane] = 1.0f / ltot;
#pragma unroll
    for (int r = 0; r < 16; ++r) {
      const int qloc = (r & 3) + 8 * (r >> 2) + 4 * hi;
      const float inv = Linv2[qgrp][qloc];
      const int qrow = qt * 64 + qgrp * 32 + qloc;
      bf16* cp = ctx + (size_t)(b * SEQ + qrow) * EMB + h * HD;
      cp[l31] = (bf16)(o0[r] * inv);
      cp[32 + l31] = (bf16)(o1[r] * inv);
    }
  }
}

// ---------------- residual + LayerNorm ----------------
__global__ __launch_bounds__(256) void ln1_k(
    const float* __restrict__ x, const float* __restrict__ ao,
    const float* __restrict__ g, const float* __restrict__ bta,
    float* __restrict__ hF, bf16* __restrict__ hB) {
  int row = blockIdx.x, tid = threadIdx.x;
  const float* xr = x + (size_t)row * EMB;
  const float* ar = ao + (size_t)row * EMB;
  float v[4], s = 0.0f, s2 = 0.0f;
#pragma unroll
  for (int i = 0; i < 4; ++i) {
    float t = xr[tid + i * 256] + ar[tid + i * 256];
    v[i] = t; s += t; s2 += t * t;
  }
#pragma unroll
  for (int off = 1; off < 64; off <<= 1) {
    s += __shfl_xor(s, off, 64);
    s2 += __shfl_xor(s2, off, 64);
  }
  __shared__ float red[8];
  int wave = tid >> 6, lane = tid & 63;
  if (lane == 0) { red[wave] = s; red[4 + wave] = s2; }
  __syncthreads();
  s = red[0] + red[1] + red[2] + red[3];
  s2 = red[4] + red[5] + red[6] + red[7];
  float mean = s * (1.0f / EMB);
  float var = s2 * (1.0f / EMB) - mean * mean;
  float inv = rsqrtf(var + 1e-5f);
#pragma unroll
  for (int i = 0; i < 4; ++i) {
    int c = tid + i * 256;
    float t = (v[i] - mean) * inv * g[c] + bta[c];
    hF[(size_t)row * EMB + c] = t;
    hB[(size_t)row * EMB + c] = (bf16)t;
  }
}

__global__ __launch_bounds__(256) void geglu_ln2(
    const float* __restrict__ h, const bf16* __restrict__ proj,
    const float* __restrict__ g, const float* __restrict__ bta,
    float* __restrict__ out) {
  int row = blockIdx.x, tid = threadIdx.x;
  const float* hr = h + (size_t)row * EMB;
  const bf16* pr = proj + (size_t)row * 2048;
  float v[4], s = 0.0f, s2 = 0.0f;
#pragma unroll
  for (int i = 0; i < 4; ++i) {
    int c = tid + i * 256;
    float val = (float)pr[c];
    float gate = (float)pr[1024 + c];
    float ge = 0.5f * gate * (1.0f + erff(gate * 0.70710678f));
    float t = hr[c] + val * ge;
    v[i] = t; s += t; s2 += t * t;
  }
#pragma unroll
  for (int off = 1; off < 64; off <<= 1) {
    s += __shfl_xor(s, off, 64);
    s2 += __shfl_xor(s2, off, 64);
  }
  __shared__ float red[8];
  int wave = tid >> 6, lane = tid & 63;
  if (lane == 0) { red[wave] = s; red[4 + wave] = s2; }
  __syncthreads();
  s = red[0] + red[1] + red[2] + red[3];
  s2 = red[4] + red[5] + red[6] + red[7];
  float mean = s * (1.0f / EMB);
  float var = s2 * (1.0f / EMB) - mean * mean;
  float inv = rsqrtf(var + 1e-5f);
#pragma unroll
  for (int i = 0; i < 4; ++i) {
    int c = tid + i * 256;
    out[(size_t)row * EMB + c] = (v[i] - mean) * inv * g[c] + bta[c];
  }
}

extern "C" void kernel_launch(void* const* d_in, const int* in_sizes, int n_in,
                              void* d_out, int out_size, void* d_ws, size_t ws_size,
                              hipStream_t stream) {
  const float* x = (const float*)d_in[0];
  const float* inW = (const float*)d_in[1];
  const float* inB = (const float*)d_in[2];
  const float* outW = (const float*)d_in[3];
  const float* opB = (const float*)d_in[4];
  const float* ggW = (const float*)d_in[5];
  const float* ggB = (const float*)d_in[6];
  const float* g1 = (const float*)d_in[7];
  const float* b1 = (const float*)d_in[8];
  const float* g2 = (const float*)d_in[9];
  const float* b2 = (const float*)d_in[10];
  float* out = (float*)d_out;
  char* ws = (char*)d_ws;
  const size_t MB = 1ull << 20;
  bf16* xb = (bf16*)(ws);              // 8 MB
  bf16* qr = (bf16*)(ws + 8 * MB);     // 8 MB, dead after in-proj
  bf16* ctx = (bf16*)(ws + 8 * MB);    // overlays qr (attn output)
  bf16* wI = (bf16*)(ws + 16 * MB);    // 6 MB
  bf16* wO = (bf16*)(ws + 22 * MB);    // 2 MB
  bf16* wG = (bf16*)(ws + 24 * MB);    // 4 MB
  bf16* qk = (bf16*)(ws + 28 * MB);    // 16 MB, dead after attn
  bf16* projB = (bf16*)(ws + 28 * MB); // overlays qk
  bf16* vbT = (bf16*)(ws + 44 * MB);   // 8 MB V^T, dead after attn
  float* ao = (float*)(ws + 44 * MB);  // 16 MB f32, overlays vbT
  bf16* hB = (bf16*)(ws + 60 * MB);    // 8 MB

  rope_cast<<<NTOK * 512 / 256, 256, 0, stream>>>(x, xb, qr);
  cast_w<<<(3072 * 1024 / 4) / 256, 256, 0, stream>>>(inW, wI, 3072 * 1024);
  cast_w<<<(1024 * 1024 / 4) / 256, 256, 0, stream>>>(outW, wO, 1024 * 1024);
  cast_w<<<(2048 * 1024 / 4) / 256, 256, 0, stream>>>(ggW, wG, 2048 * 1024);
  gemm_in<<<dim3(24, 32), 256, 0, stream>>>(qr, xb, wI, inB, qk, vbT);
  attn8<<<1024, 256, 0, stream>>>(qk, vbT, ctx);
  gemm_bt64<<<dim3(16, 32), 256, 0, stream>>>(ctx, wO, opB, ao,
                                              NTOK, 1024, 1024);
  ln1_k<<<NTOK, 256, 0, stream>>>(x, ao, g1, b1, ao, hB);
  gemm_bt<<<dim3(16, 32), 256, 0, stream>>>(hB, wG, ggB, nullptr, projB,
                                            NTOK, 2048, 1024);
  geglu_ln2<<<NTOK, 256, 0, stream>>>(ao, projB, g2, b2, out);
}

// Round 8
// 272.471 us; speedup vs baseline: 1.0350x; 1.0350x over previous
//
#include <hip/hip_runtime.h>

// TransformerBlock on MI355X (gfx950).
// Fused in-proj (q,k from RoPE(x); v from x, written transposed), 16-head
// flash attention (D=64): 32x32x16 MFMA, S^T = K·Q^T, P stays in registers
// (V key-columns permuted in LDS so PV A-frag = S^T C-quads directly).
// v9: 128-key tiles per barrier (two independent 64-key compute streams per
// iteration for in-wave ILP; 16 iters), double-buffered K/V (64 KB LDS),
// XCD-swizzled grid. Then out-proj, res+LN1, GeGLU, res+LN2.

typedef __bf16 bf16;
typedef bf16 bf16x8 __attribute__((ext_vector_type(8)));
typedef bf16 bf16x4 __attribute__((ext_vector_type(4)));
typedef float f32x4 __attribute__((ext_vector_type(4)));
typedef float f32x16 __attribute__((ext_vector_type(16)));

#define EMB 1024
#define SEQ 2048
#define NTOK 4096
#define NH 16
#define HD 64

__device__ __forceinline__ f32x4 mfma16(bf16x8 a, bf16x8 b, f32x4 c) {
  return __builtin_amdgcn_mfma_f32_16x16x32_bf16(a, b, c, 0, 0, 0);
}
__device__ __forceinline__ f32x16 mfma32(bf16x8 a, bf16x8 b, f32x16 c) {
  return __builtin_amdgcn_mfma_f32_32x32x16_bf16(a, b, c, 0, 0, 0);
}

__device__ __forceinline__ void gll16(const void* g, void* l) {
  __builtin_amdgcn_global_load_lds(
      (const __attribute__((address_space(1))) void*)g,
      (__attribute__((address_space(3))) void*)l, 16, 0, 0);
}

__device__ __forceinline__ unsigned pk2(float a, float b) {
  union { bf16 h[2]; unsigned u; } t;
  t.h[0] = (bf16)a; t.h[1] = (bf16)b;
  return t.u;
}

// ---------------- elementwise prep ----------------

__global__ __launch_bounds__(256) void rope_cast(
    const float* __restrict__ x, bf16* __restrict__ xb, bf16* __restrict__ qr) {
  int idx = blockIdx.x * 256 + threadIdx.x;   // 0 .. NTOK*512
  int row = idx >> 9;
  int i = idx & 511;
  int h = i >> 5, d2 = i & 31;
  int pos = row & (SEQ - 1);
  int c0 = h * HD + d2;
  size_t base = (size_t)row * EMB;
  float x0 = x[base + c0], x1 = x[base + c0 + 32];
  float invf = exp2f(-(float)d2 * 0.4152410118609203f);
  float ang = (float)pos * invf;
  float sn, cs;
  sincosf(ang, &sn, &cs);
  qr[base + c0] = (bf16)(x0 * cs - x1 * sn);
  qr[base + c0 + 32] = (bf16)(x1 * cs + x0 * sn);
  xb[base + c0] = (bf16)x0;
  xb[base + c0 + 32] = (bf16)x1;
}

__global__ __launch_bounds__(256) void cast_w(
    const float* __restrict__ w, bf16* __restrict__ o, int n) {
  int i = (blockIdx.x * 256 + threadIdx.x) * 4;
  if (i < n) {
    float4 f = *(const float4*)(w + i);
    o[i] = (bf16)f.x; o[i + 1] = (bf16)f.y;
    o[i + 2] = (bf16)f.z; o[i + 3] = (bf16)f.w;
  }
}

// ---------------- fused in-proj GEMM ----------------
__global__ __launch_bounds__(256) void gemm_in(
    const bf16* __restrict__ Aq, const bf16* __restrict__ Ax,
    const bf16* __restrict__ W, const float* __restrict__ bias,
    bf16* __restrict__ qk, bf16* __restrict__ vT) {
  __shared__ bf16 As[128 * 32];
  __shared__ bf16 Bs[128 * 32];
  const int tid = threadIdx.x, lane = tid & 63, wave = tid >> 6;
  const int quad = lane >> 4, l16 = lane & 15;
  const int m0 = blockIdx.y * 128, n0 = blockIdx.x * 128;
  const bf16* A = (n0 < 2048) ? Aq : Ax;
  const int K = 1024;
  const int wm = (wave >> 1) * 64, wn = (wave & 1) * 64;
  const int srow = wave * 32 + (lane >> 2);
  const int scol = (lane & 3) * 8;
  f32x4 acc[4][4] = {};
  for (int k0 = 0; k0 < K; k0 += 32) {
    __syncthreads();
    gll16(A + (size_t)(m0 + srow) * K + k0 + scol, As + wave * 1024);
    gll16(A + (size_t)(m0 + srow + 16) * K + k0 + scol, As + wave * 1024 + 512);
    gll16(W + (size_t)(n0 + srow) * K + k0 + scol, Bs + wave * 1024);
    gll16(W + (size_t)(n0 + srow + 16) * K + k0 + scol, Bs + wave * 1024 + 512);
    __syncthreads();
    bf16x8 af[4], bw[4];
#pragma unroll
    for (int t = 0; t < 4; ++t) {
      af[t] = *(const bf16x8*)(As + (wm + t * 16 + l16) * 32 + quad * 8);
      bw[t] = *(const bf16x8*)(Bs + (wn + t * 16 + l16) * 32 + quad * 8);
    }
#pragma unroll
    for (int mt = 0; mt < 4; ++mt)
#pragma unroll
      for (int nt = 0; nt < 4; ++nt)
        acc[mt][nt] = mfma16(af[mt], bw[nt], acc[mt][nt]);
  }
  if (n0 < 2048) {
#pragma unroll
    for (int mt = 0; mt < 4; ++mt)
      for (int nt = 0; nt < 4; ++nt) {
        const int n = n0 + wn + nt * 16 + l16;
        const float bv = bias[n];
#pragma unroll
        for (int r = 0; r < 4; ++r) {
          const int m = m0 + wm + mt * 16 + quad * 4 + r;
          qk[(size_t)m * 2048 + n] = (bf16)(acc[mt][nt][r] + bv);
        }
      }
  } else {
#pragma unroll
    for (int mt = 0; mt < 4; ++mt)
      for (int nt = 0; nt < 4; ++nt) {
        const int n = n0 + wn + nt * 16 + l16;
        const float bv = bias[n];
        const int m = m0 + wm + mt * 16 + quad * 4;
        const int bb = m >> 11, s = m & 2047;
        bf16x4 pkv;
#pragma unroll
        for (int r = 0; r < 4; ++r) pkv[r] = (bf16)(acc[mt][nt][r] + bv);
        *(bf16x4*)(vT + (((size_t)bb * 1024 + (n - 2048)) << 11) + s) = pkv;
      }
  }
}

// ---------------- GEMM 128x128: C = A @ W^T + bias ----------------
__global__ __launch_bounds__(256) void gemm_bt(
    const bf16* __restrict__ A, const bf16* __restrict__ W,
    const float* __restrict__ bias,
    float* __restrict__ outF, bf16* __restrict__ outB,
    int M, int N, int K) {
  __shared__ bf16 As[128 * 32];
  __shared__ bf16 Bs[128 * 32];
  const int tid = threadIdx.x, lane = tid & 63, wave = tid >> 6;
  const int quad = lane >> 4, l16 = lane & 15;
  const int m0 = blockIdx.y * 128, n0 = blockIdx.x * 128;
  const int wm = (wave >> 1) * 64, wn = (wave & 1) * 64;
  const int srow = wave * 32 + (lane >> 2);
  const int scol = (lane & 3) * 8;
  f32x4 acc[4][4] = {};
  for (int k0 = 0; k0 < K; k0 += 32) {
    __syncthreads();
    gll16(A + (size_t)(m0 + srow) * K + k0 + scol, As + wave * 1024);
    gll16(A + (size_t)(m0 + srow + 16) * K + k0 + scol, As + wave * 1024 + 512);
    gll16(W + (size_t)(n0 + srow) * K + k0 + scol, Bs + wave * 1024);
    gll16(W + (size_t)(n0 + srow + 16) * K + k0 + scol, Bs + wave * 1024 + 512);
    __syncthreads();
    bf16x8 af[4], bw[4];
#pragma unroll
    for (int t = 0; t < 4; ++t) {
      af[t] = *(const bf16x8*)(As + (wm + t * 16 + l16) * 32 + quad * 8);
      bw[t] = *(const bf16x8*)(Bs + (wn + t * 16 + l16) * 32 + quad * 8);
    }
#pragma unroll
    for (int mt = 0; mt < 4; ++mt)
#pragma unroll
      for (int nt = 0; nt < 4; ++nt)
        acc[mt][nt] = mfma16(af[mt], bw[nt], acc[mt][nt]);
  }
#pragma unroll
  for (int mt = 0; mt < 4; ++mt)
    for (int nt = 0; nt < 4; ++nt) {
      const int n = n0 + wn + nt * 16 + l16;
      const float bv = bias ? bias[n] : 0.0f;
#pragma unroll
      for (int r = 0; r < 4; ++r) {
        const int m = m0 + wm + mt * 16 + quad * 4 + r;
        const float v = acc[mt][nt][r] + bv;
        if (outF) outF[(size_t)m * N + n] = v;
        if (outB) outB[(size_t)m * N + n] = (bf16)v;
      }
    }
}

// ---------------- GEMM 128x64 tiles ----------------
__global__ __launch_bounds__(256) void gemm_bt64(
    const bf16* __restrict__ A, const bf16* __restrict__ W,
    const float* __restrict__ bias, float* __restrict__ outF,
    int M, int N, int K) {
  __shared__ bf16 As[128 * 32];
  __shared__ bf16 Bs[64 * 32];
  const int tid = threadIdx.x, lane = tid & 63, wave = tid >> 6;
  const int quad = lane >> 4, l16 = lane & 15;
  const int m0 = blockIdx.y * 128, n0 = blockIdx.x * 64;
  const int wm = (wave >> 1) * 64, wn = (wave & 1) * 32;
  const int srow = wave * 32 + (lane >> 2);
  const int srowB = wave * 16 + (lane >> 2);
  const int scol = (lane & 3) * 8;
  f32x4 acc[4][2] = {};
  for (int k0 = 0; k0 < K; k0 += 32) {
    __syncthreads();
    gll16(A + (size_t)(m0 + srow) * K + k0 + scol, As + wave * 1024);
    gll16(A + (size_t)(m0 + srow + 16) * K + k0 + scol, As + wave * 1024 + 512);
    gll16(W + (size_t)(n0 + srowB) * K + k0 + scol, Bs + wave * 512);
    __syncthreads();
    bf16x8 af[4], bw[2];
#pragma unroll
    for (int t = 0; t < 4; ++t)
      af[t] = *(const bf16x8*)(As + (wm + t * 16 + l16) * 32 + quad * 8);
#pragma unroll
    for (int t = 0; t < 2; ++t)
      bw[t] = *(const bf16x8*)(Bs + (wn + t * 16 + l16) * 32 + quad * 8);
#pragma unroll
    for (int mt = 0; mt < 4; ++mt)
#pragma unroll
      for (int nt = 0; nt < 2; ++nt)
        acc[mt][nt] = mfma16(af[mt], bw[nt], acc[mt][nt]);
  }
#pragma unroll
  for (int mt = 0; mt < 4; ++mt)
    for (int nt = 0; nt < 2; ++nt) {
      const int n = n0 + wn + nt * 16 + l16;
      const float bv = bias[n];
#pragma unroll
      for (int r = 0; r < 4; ++r) {
        const int m = m0 + wm + mt * 16 + quad * 4 + r;
        outF[(size_t)m * N + n] = acc[mt][nt][r] + bv;
      }
    }
}

// ---------------- flash attention v9: 128-key tiles, dual stream ----------------
// 512 blocks (XCD-swizzled), block = 128 q-rows, 4 waves x 32 q.
// Per barrier: 128 keys staged (K[128][64], Vperm[64][128]); compute runs two
// independent 64-key halves so S-MFMA of one overlaps exp/PV of the other.
__global__ __launch_bounds__(256) void attn9(
    const bf16* __restrict__ QK, const bf16* __restrict__ VT,
    bf16* __restrict__ ctx) {
  __shared__ __align__(16) bf16 Ks[2][8192];   // [key 0..127][d 0..63] swizzled
  __shared__ __align__(16) bf16 Vs[2][8192];   // [d 0..63][key perm 0..127] swizzled
  __shared__ float Linv[4][32];
  const int tid = threadIdx.x, lane = tid & 63, wave = tid >> 6;
  const int hi = lane >> 5, l31 = lane & 31, l7 = lane & 7;
  const int bid = blockIdx.x;
  const int hb = (bid & 7) * 4 + ((bid >> 3) & 3);
  const int qt = bid >> 5;              // 0..15
  const int h = hb & 15, b = hb >> 4;

  // Q B-frags (lane owns col q = l31; k=d=tt*16+hi*8+j), pre-scaled 0.125
  bf16x8 qf[4];
  {
    const int qrow = qt * 128 + wave * 32 + l31;
    const bf16* qp = QK + (size_t)(b * SEQ + qrow) * 2048 + h * HD + hi * 8;
#pragma unroll
    for (int t = 0; t < 4; ++t) {
      bf16x8 v = *(const bf16x8*)(qp + t * 16);
#pragma unroll
      for (int j = 0; j < 8; ++j) v[j] = (bf16)((float)v[j] * 0.125f);
      qf[t] = v;
    }
  }
  f32x16 o0 = {}, o1 = {};
  float lpart = 0.0f;

  // staging indices
  const int krow0 = tid >> 3;          // K rows krow0 + {0,32,64,96}
  const int ksc = tid & 7;             // K 16B chunk
  const int vrow0 = tid >> 4;          // V rows vrow0 + {0,16,32,48}
  const int vc16 = tid & 15;           // V 16B chunk (of 16)
  const int og = (vc16 >> 1) * 16 + (vc16 & 1) * 4;   // permuted gather base
  const bf16* kg = QK + (size_t)(b * SEQ) * 2048 + 1024 + h * HD + ksc * 8;
  const bf16* vg = VT + ((size_t)(b * NH + h) * HD) * 2048;

  bf16x8 kcur[4];
  uint2 va[4], vb[4];
#pragma unroll
  for (int p = 0; p < 4; ++p) {   // load tile 0
    kcur[p] = *(const bf16x8*)(kg + (size_t)(krow0 + p * 32) * 2048);
    va[p] = *(const uint2*)(vg + (size_t)(vrow0 + p * 16) * 2048 + og);
    vb[p] = *(const uint2*)(vg + (size_t)(vrow0 + p * 16) * 2048 + og + 8);
  }
#pragma unroll
  for (int p = 0; p < 4; ++p) {   // stage tile 0 into buf 0
    const int kr = krow0 + p * 32;
    *(bf16x8*)(Ks[0] + kr * 64 + ((ksc ^ (kr & 7)) * 8)) = kcur[p];
    const int vr = vrow0 + p * 16;
    union { uint2 u2[2]; bf16x8 v; } vv;
    vv.u2[0] = va[p]; vv.u2[1] = vb[p];
    *(bf16x8*)(Vs[0] + vr * 128 + ((vc16 ^ (vr & 7)) * 8)) = vv.v;
  }
#pragma unroll
  for (int p = 0; p < 4; ++p) {   // prefetch tile 1
    kcur[p] = *(const bf16x8*)(kg + (size_t)(128 + krow0 + p * 32) * 2048);
    va[p] = *(const uint2*)(vg + (size_t)(vrow0 + p * 16) * 2048 + 128 + og);
    vb[p] = *(const uint2*)(vg + (size_t)(vrow0 + p * 16) * 2048 + 128 + og + 8);
  }

  for (int t = 0; t < 16; ++t) {
    __syncthreads();
    const bf16* ks = Ks[t & 1];
    const bf16* vs = Vs[t & 1];
    if (t + 1 < 16) {
      bf16* kd = Ks[(t + 1) & 1];
      bf16* vd = Vs[(t + 1) & 1];
#pragma unroll
      for (int p = 0; p < 4; ++p) {
        const int kr = krow0 + p * 32;
        *(bf16x8*)(kd + kr * 64 + ((ksc ^ (kr & 7)) * 8)) = kcur[p];
        const int vr = vrow0 + p * 16;
        union { uint2 u2[2]; bf16x8 v; } vv;
        vv.u2[0] = va[p]; vv.u2[1] = vb[p];
        *(bf16x8*)(vd + vr * 128 + ((vc16 ^ (vr & 7)) * 8)) = vv.v;
      }
      if (t + 2 < 16) {
        const int kb2 = (t + 2) * 128;
#pragma unroll
        for (int p = 0; p < 4; ++p) {
          kcur[p] = *(const bf16x8*)(kg + (size_t)(kb2 + krow0 + p * 32) * 2048);
          va[p] = *(const uint2*)(vg + (size_t)(vrow0 + p * 16) * 2048 + kb2 + og);
          vb[p] = *(const uint2*)(vg + (size_t)(vrow0 + p * 16) * 2048 + kb2 + og + 8);
        }
      }
    }
    // two independent 64-key halves
#pragma unroll
    for (int half = 0; half < 2; ++half) {
      const bf16* ksh = ks + half * 64 * 64;
      f32x16 s0 = {}, s1 = {};
#pragma unroll
      for (int tt = 0; tt < 4; ++tt) {
        const int swc = ((tt * 2 + hi) ^ l7) * 8;
        bf16x8 k0 = *(const bf16x8*)(ksh + l31 * 64 + swc);
        bf16x8 k1 = *(const bf16x8*)(ksh + (32 + l31) * 64 + swc);
        s0 = mfma32(k0, qf[tt], s0);
        s1 = mfma32(k1, qf[tt], s1);
      }
      unsigned u[16];
#pragma unroll
      for (int g = 0; g < 8; ++g) {
        const int base = (g & 3) * 4;
        float e0, e1, e2, e3;
        if (g < 4) {
          e0 = __expf(s0[base]); e1 = __expf(s0[base + 1]);
          e2 = __expf(s0[base + 2]); e3 = __expf(s0[base + 3]);
        } else {
          e0 = __expf(s1[base]); e1 = __expf(s1[base + 1]);
          e2 = __expf(s1[base + 2]); e3 = __expf(s1[base + 3]);
        }
        lpart += (e0 + e1) + (e2 + e3);
        u[g * 2] = pk2(e0, e1);
        u[g * 2 + 1] = pk2(e2, e3);
      }
      // PV: chunk16 = (8*half + 2kk + hi) ^ l7; bit3 passes through XOR
#pragma unroll
      for (int kk = 0; kk < 4; ++kk) {
        union { unsigned w[4]; bf16x8 v; } fw;
        fw.w[0] = u[4 * kk]; fw.w[1] = u[4 * kk + 1];
        fw.w[2] = u[4 * kk + 2]; fw.w[3] = u[4 * kk + 3];
        const int c16 = (8 * half + 2 * kk + hi) ^ l7;
        bf16x8 v0 = *(const bf16x8*)(vs + l31 * 128 + c16 * 8);
        bf16x8 v1 = *(const bf16x8*)(vs + (32 + l31) * 128 + c16 * 8);
        o0 = mfma32(fw.v, v0, o0);
        o1 = mfma32(fw.v, v1, o1);
      }
    }
  }
  // epilogue
  float ltot = lpart + __shfl_xor(lpart, 32, 64);
  if (lane < 32) Linv[wave][lane] = 1.0f / ltot;
#pragma unroll
  for (int r = 0; r < 16; ++r) {
    const int qloc = (r & 3) + 8 * (r >> 2) + 4 * hi;
    const float inv = Linv[wave][qloc];
    const int qrow = qt * 128 + wave * 32 + qloc;
    bf16* cp = ctx + (size_t)(b * SEQ + qrow) * EMB + h * HD;
    cp[l31] = (bf16)(o0[r] * inv);
    cp[32 + l31] = (bf16)(o1[r] * inv);
  }
}

// ---------------- residual + LayerNorm ----------------
__global__ __launch_bounds__(256) void ln1_k(
    const float* __restrict__ x, const float* __restrict__ ao,
    const float* __restrict__ g, const float* __restrict__ bta,
    float* __restrict__ hF, bf16* __restrict__ hB) {
  int row = blockIdx.x, tid = threadIdx.x;
  const float* xr = x + (size_t)row * EMB;
  const float* ar = ao + (size_t)row * EMB;
  float v[4], s = 0.0f, s2 = 0.0f;
#pragma unroll
  for (int i = 0; i < 4; ++i) {
    float t = xr[tid + i * 256] + ar[tid + i * 256];
    v[i] = t; s += t; s2 += t * t;
  }
#pragma unroll
  for (int off = 1; off < 64; off <<= 1) {
    s += __shfl_xor(s, off, 64);
    s2 += __shfl_xor(s2, off, 64);
  }
  __shared__ float red[8];
  int wave = tid >> 6, lane = tid & 63;
  if (lane == 0) { red[wave] = s; red[4 + wave] = s2; }
  __syncthreads();
  s = red[0] + red[1] + red[2] + red[3];
  s2 = red[4] + red[5] + red[6] + red[7];
  float mean = s * (1.0f / EMB);
  float var = s2 * (1.0f / EMB) - mean * mean;
  float inv = rsqrtf(var + 1e-5f);
#pragma unroll
  for (int i = 0; i < 4; ++i) {
    int c = tid + i * 256;
    float t = (v[i] - mean) * inv * g[c] + bta[c];
    hF[(size_t)row * EMB + c] = t;
    hB[(size_t)row * EMB + c] = (bf16)t;
  }
}

__global__ __launch_bounds__(256) void geglu_ln2(
    const float* __restrict__ h, const bf16* __restrict__ proj,
    const float* __restrict__ g, const float* __restrict__ bta,
    float* __restrict__ out) {
  int row = blockIdx.x, tid = threadIdx.x;
  const float* hr = h + (size_t)row * EMB;
  const bf16* pr = proj + (size_t)row * 2048;
  float v[4], s = 0.0f, s2 = 0.0f;
#pragma unroll
  for (int i = 0; i < 4; ++i) {
    int c = tid + i * 256;
    float val = (float)pr[c];
    float gate = (float)pr[1024 + c];
    float ge = 0.5f * gate * (1.0f + erff(gate * 0.70710678f));
    float t = hr[c] + val * ge;
    v[i] = t; s += t; s2 += t * t;
  }
#pragma unroll
  for (int off = 1; off < 64; off <<= 1) {
    s += __shfl_xor(s, off, 64);
    s2 += __shfl_xor(s2, off, 64);
  }
  __shared__ float red[8];
  int wave = tid >> 6, lane = tid & 63;
  if (lane == 0) { red[wave] = s; red[4 + wave] = s2; }
  __syncthreads();
  s = red[0] + red[1] + red[2] + red[3];
  s2 = red[4] + red[5] + red[6] + red[7];
  float mean = s * (1.0f / EMB);
  float var = s2 * (1.0f / EMB) - mean * mean;
  float inv = rsqrtf(var + 1e-5f);
#pragma unroll
  for (int i = 0; i < 4; ++i) {
    int c = tid + i * 256;
    out[(size_t)row * EMB + c] = (v[i] - mean) * inv * g[c] + bta[c];
  }
}

extern "C" void kernel_launch(void* const* d_in, const int* in_sizes, int n_in,
                              void* d_out, int out_size, void* d_ws, size_t ws_size,
                              hipStream_t stream) {
  const float* x = (const float*)d_in[0];
  const float* inW = (const float*)d_in[1];
  const float* inB = (const float*)d_in[2];
  const float* outW = (const float*)d_in[3];
  const float* opB = (const float*)d_in[4];
  const float* ggW = (const float*)d_in[5];
  const float* ggB = (const float*)d_in[6];
  const float* g1 = (const float*)d_in[7];
  const float* b1 = (const float*)d_in[8];
  const float* g2 = (const float*)d_in[9];
  const float* b2 = (const float*)d_in[10];
  float* out = (float*)d_out;
  char* ws = (char*)d_ws;
  const size_t MB = 1ull << 20;
  bf16* xb = (bf16*)(ws);              // 8 MB
  bf16* qr = (bf16*)(ws + 8 * MB);     // 8 MB, dead after in-proj
  bf16* ctx = (bf16*)(ws + 8 * MB);    // overlays qr (attn output)
  bf16* wI = (bf16*)(ws + 16 * MB);    // 6 MB
  bf16* wO = (bf16*)(ws + 22 * MB);    // 2 MB
  bf16* wG = (bf16*)(ws + 24 * MB);    // 4 MB
  bf16* qk = (bf16*)(ws + 28 * MB);    // 16 MB, dead after attn
  bf16* projB = (bf16*)(ws + 28 * MB); // overlays qk
  bf16* vbT = (bf16*)(ws + 44 * MB);   // 8 MB V^T, dead after attn
  float* ao = (float*)(ws + 44 * MB);  // 16 MB f32, overlays vbT
  bf16* hB = (bf16*)(ws + 60 * MB);    // 8 MB

  rope_cast<<<NTOK * 512 / 256, 256, 0, stream>>>(x, xb, qr);
  cast_w<<<(3072 * 1024 / 4) / 256, 256, 0, stream>>>(inW, wI, 3072 * 1024);
  cast_w<<<(1024 * 1024 / 4) / 256, 256, 0, stream>>>(outW, wO, 1024 * 1024);
  cast_w<<<(2048 * 1024 / 4) / 256, 256, 0, stream>>>(ggW, wG, 2048 * 1024);
  gemm_in<<<dim3(24, 32), 256, 0, stream>>>(qr, xb, wI, inB, qk, vbT);
  attn9<<<512, 256, 0, stream>>>(qk, vbT, ctx);
  gemm_bt64<<<dim3(16, 32), 256, 0, stream>>>(ctx, wO, opB, ao,
                                              NTOK, 1024, 1024);
  ln1_k<<<NTOK, 256, 0, stream>>>(x, ao, g1, b1, ao, hB);
  gemm_bt<<<dim3(16, 32), 256, 0, stream>>>(hB, wG, ggB, nullptr, projB,
                                            NTOK, 2048, 1024);
  geglu_ln2<<<NTOK, 256, 0, stream>>>(ao, projB, g2, b2, out);
}